// Round 4
// baseline (399.237 us; speedup 1.0000x reference)
//
#include <hip/hip_runtime.h>
#include <stdint.h>
#include <float.h>

// x[4096,256] f32, keys[65536,256] f32, values[65536,10] f32, k=8 (hardcoded).
#define B_ROWS 4096
#define N_KEYS 65536
#define DDIM 256
#define NCH 10

#define NSPLIT 8
#define SPLIT_KEYS (N_KEYS / NSPLIT)       // 8192
#define ROWS_PER_BLK 64
#define CHUNK_KEYS 64
#define NCHUNK (SPLIT_KEYS / CHUNK_KEYS)   // 128
#define NSTREAM 8

typedef float f32x4 __attribute__((ext_vector_type(4)));
typedef short bf16x8 __attribute__((ext_vector_type(8)));

static __device__ __forceinline__ unsigned short f2bf(float f) {
  unsigned u = __float_as_uint(f);
  return (unsigned short)((u + 0x7FFFu + ((u >> 16) & 1u)) >> 16);
}
static __device__ __forceinline__ unsigned ford(float f) {
  unsigned u = __float_as_uint(f);
  return u ^ ((unsigned)((int)u >> 31) | 0x80000000u);
}
static __device__ __forceinline__ float ford_inv(unsigned u) {
  unsigned m = 0x80000000u | ((u >> 31) - 1u);
  return __uint_as_float(u ^ m);
}
static __device__ __forceinline__ unsigned long long shfl_xor_u64(unsigned long long v, int m) {
  unsigned lo = __shfl_xor((unsigned)v, m, 64);
  unsigned hi = __shfl_xor((unsigned)(v >> 32), m, 64);
  return ((unsigned long long)hi << 32) | lo;
}
static __device__ __forceinline__ double shfl_xor_f64(double v, int m) {
  return __longlong_as_double((long long)shfl_xor_u64((unsigned long long)__double_as_longlong(v), m));
}
static __device__ __forceinline__ void gl_lds16(const void* g, void* l) {
  __builtin_amdgcn_global_load_lds(
      (const __attribute__((address_space(1))) unsigned int*)g,
      (__attribute__((address_space(3))) unsigned int*)l, 16, 0, 0);
}

// ---------------------------------------------------------------------------
// transpose_keys: bf16-convert + transpose + fused ksq. Output layout:
// [chunk64][koct 0..31][key64 0..63][16B] (32KB records) so knn_main staging
// is a LINEAR 32KB copy and A-frag ds_read_b128s are 256B-contiguous per
// 16-lane phase (conflict-free). One 128-key region per 256-thr block.
// ---------------------------------------------------------------------------
__global__ __launch_bounds__(256) void transpose_keys(const float* __restrict__ keys,
                                                      unsigned char* __restrict__ kbf,
                                                      float* __restrict__ ksq) {
  __shared__ __align__(16) unsigned char T[128 * 512]; // XOR-swizzled scratch
  const int t = threadIdx.x;
  const int lane = t & 63;
  const int wv = t >> 6;
  const float4* src = (const float4*)(keys + (size_t)blockIdx.x * 128 * DDIM);
#pragma unroll
  for (int j = 0; j < 32; ++j) {
    int g = j * 256 + t;            // float4 index; key = j*4+wv, rem = lane
    float4 v = src[g];
    int key = g >> 6;
    int u = lane >> 1, sub = lane & 1;
    unsigned lo = ((unsigned)f2bf(v.y) << 16) | f2bf(v.x);
    unsigned hi2 = ((unsigned)f2bf(v.w) << 16) | f2bf(v.z);
    unsigned long long p = ((unsigned long long)hi2 << 32) | lo;
    *(unsigned long long*)&T[key * 512 + ((u ^ (key & 7)) << 4) + (sub << 3)] = p;
    // fused squared norm (wave covers exactly one key per j)
    float ss = v.x * v.x + v.y * v.y + v.z * v.z + v.w * v.w;
#pragma unroll
    for (int off = 32; off; off >>= 1) ss += __shfl_xor(ss, off, 64);
    if (lane == 0) ksq[blockIdx.x * 128 + key] = ss;
  }
  __syncthreads();
  uint4* dst = (uint4*)(kbf + (size_t)blockIdx.x * 65536);
#pragma unroll
  for (int j = 0; j < 16; ++j) {
    int ou = j * 256 + t;           // 16B unit in 64KB (2 chunk64 records)
    int c64 = ou >> 11, rem = ou & 2047;
    int koct = rem >> 6, key64 = rem & 63;
    int keyl = c64 * 64 + key64;
    dst[ou] = *(const uint4*)&T[keyl * 512 + ((koct ^ (keyl & 7)) << 4)];
  }
}

// ---------------------------------------------------------------------------
// knn_main: 256 thr = 4 waves = 2 key-halves (mw) x 2 row-quads (ws, 32 rows).
// 64 rows x one split (8192 keys) in 128 chunks of 64 keys.
// Pipeline (T3/T4): double-buffered 32KB tiles via global_load_lds, counted
// s_waitcnt vmcnt(10) at tile-entry barrier (next chunk's 8 staging + 2 ksq
// loads stay IN FLIGHT), lgkmcnt(0) at tile-exit barrier. Never drains to 0.
// 65KB LDS/block -> 2 blocks/CU. Selection: tau-gated per-thread top-8
// (pigeonhole over 8 streams/row; proof as r3).
// ---------------------------------------------------------------------------
__global__ __launch_bounds__(256, 2) void knn_main(
    const float* __restrict__ x,
    const unsigned char* __restrict__ kbf,
    const float* __restrict__ ksqg,
    unsigned long long* __restrict__ cand) {
  __shared__ __align__(16) unsigned char tiles[2][32768]; // 64KB double buffer
  __shared__ float tauh[2][2][2][2][16]; // [par][set][ws][mw][lo4] = 1KB

  const int t = threadIdx.x;
  const int lane = t & 63;
  const int wv = t >> 6;          // 0..3
  const int mw = wv & 1;          // key half (32 keys)
  const int ws = wv >> 1;         // row quad (32 rows)
  const int lo4 = lane & 15;
  const int hi = lane >> 4;

  const int split = blockIdx.x & (NSPLIT - 1);
  const int rb = (blockIdx.x >> 3) * ROWS_PER_BLK;
  const int sb = split * SPLIT_KEYS;

  // ---- x fragments for two 16-row sets (registers for whole kernel)
  const int xrow0 = rb + ws * 32 + lo4;
  const int xrow1 = xrow0 + 16;
  bf16x8 xb0[8], xb1[8];
#pragma unroll
  for (int s = 0; s < 8; ++s) {
    const float* p0 = x + (size_t)xrow0 * DDIM + s * 32 + hi * 8;
    const float* p1 = x + (size_t)xrow1 * DDIM + s * 32 + hi * 8;
    float4 a = *(const float4*)p0, b = *(const float4*)(p0 + 4);
    float4 c = *(const float4*)p1, d = *(const float4*)(p1 + 4);
    union { unsigned short us[8]; bf16x8 v; } u0, u1;
    u0.us[0]=f2bf(a.x); u0.us[1]=f2bf(a.y); u0.us[2]=f2bf(a.z); u0.us[3]=f2bf(a.w);
    u0.us[4]=f2bf(b.x); u0.us[5]=f2bf(b.y); u0.us[6]=f2bf(b.z); u0.us[7]=f2bf(b.w);
    u1.us[0]=f2bf(c.x); u1.us[1]=f2bf(c.y); u1.us[2]=f2bf(c.z); u1.us[3]=f2bf(c.w);
    u1.us[4]=f2bf(d.x); u1.us[5]=f2bf(d.y); u1.us[6]=f2bf(d.z); u1.us[7]=f2bf(d.w);
    xb0[s] = u0.v; xb1[s] = u1.v;
  }

  unsigned long long h0[8], h1[8];
#pragma unroll
  for (int i = 0; i < 8; ++i) { h0[i] = ~0ULL; h1[i] = ~0ULL; }
  float t8f0 = FLT_MAX, t8f1 = FLT_MAX;
  float smin0 = FLT_MAX, smin1 = FLT_MAX;

  const unsigned char* srcbase = kbf + ((size_t)split * NCHUNK << 15);
  const int kqoff = mw * 32 + hi * 4; // thread's ksq base within a chunk

  auto STAGE = [&](int c, int buf) { // linear 32KB copy, 8 gl_lds/thread
    const unsigned char* src = srcbase + ((size_t)c << 15);
    unsigned char* dstu = (unsigned char*)tiles[buf] + ((wv * 64) << 4);
#pragma unroll
    for (int i = 0; i < 8; ++i)
      gl_lds16(src + (((i * 256) + t) << 4), dstu + ((i * 256) << 4));
  };

  // ---- prologue: stage chunk 0, preload ksq chunk 0, init tau
  float4 kqc0 = *(const float4*)(ksqg + sb + kqoff);
  float4 kqc1 = *(const float4*)(ksqg + sb + kqoff + 16);
  STAGE(0, 0);
  ((float*)tauh)[t] = FLT_MAX; // 256 entries
  __syncthreads();             // prologue drain (once)

#pragma unroll 1
  for (int c = 0; c < NCHUNK; ++c) {
    const int keybase = sb + c * CHUNK_KEYS;
    const int cn = (c + 1 < NCHUNK) ? c + 1 : c; // uniform tail
    // next chunk's ksq (2 loads) + staging (8 loads) stay in flight
    float4 kqn0 = *(const float4*)(ksqg + sb + cn * 64 + kqoff);
    float4 kqn1 = *(const float4*)(ksqg + sb + cn * 64 + kqoff + 16);
    STAGE(cn, (c + 1) & 1);

    asm volatile("s_waitcnt vmcnt(10)" ::: "memory"); // chunk c's loads landed
    __builtin_amdgcn_s_barrier();

    // ---- MFMA: 32 keys x 32 rows; A-frag shared by both row sets
    const unsigned char* tile = tiles[c & 1];
    f32x4 a0[2], a1[2];
#pragma unroll
    for (int f = 0; f < 2; ++f) { a0[f] = 0.0f; a1[f] = 0.0f; }
#pragma unroll
    for (int s = 0; s < 8; ++s) {
      const unsigned char* rp = tile + (s * 4 + hi) * 1024 + (mw * 32 + lo4) * 16;
      bf16x8 af0 = *(const bf16x8*)(rp);
      bf16x8 af1 = *(const bf16x8*)(rp + 256);
      a0[0] = __builtin_amdgcn_mfma_f32_16x16x32_bf16(af0, xb0[s], a0[0], 0, 0, 0);
      a0[1] = __builtin_amdgcn_mfma_f32_16x16x32_bf16(af1, xb0[s], a0[1], 0, 0, 0);
      a1[0] = __builtin_amdgcn_mfma_f32_16x16x32_bf16(af0, xb1[s], a1[0], 0, 0, 0);
      a1[1] = __builtin_amdgcn_mfma_f32_16x16x32_bf16(af1, xb1[s], a1[1], 0, 0, 0);
    }

    // ---- scores + gated selection
    const int par = c & 1;
    const float tau0 = fmaxf(tauh[par ^ 1][0][ws][0][lo4], tauh[par ^ 1][0][ws][1][lo4]);
    const float tau1 = fmaxf(tauh[par ^ 1][1][ws][0][lo4], tauh[par ^ 1][1][ws][1][lo4]);

    float sc0[8], sc1[8];
#pragma unroll
    for (int f = 0; f < 2; ++f) {
      const float4 kq = f ? kqc1 : kqc0;
#pragma unroll
      for (int i = 0; i < 4; ++i) {
        float kqe = ((const float*)&kq)[i];
        sc0[f * 4 + i] = fmaf(-2.0f, a0[f][i], kqe);
        sc1[f * 4 + i] = fmaf(-2.0f, a1[f][i], kqe);
      }
    }
    float mb0 = sc0[0], mb1 = sc1[0];
#pragma unroll
    for (int e = 1; e < 8; ++e) { mb0 = fminf(mb0, sc0[e]); mb1 = fminf(mb1, sc1[e]); }

    auto slow = [&](const float* sc, unsigned long long* hp, float& t8, float tau) {
      float thr = fminf(t8, tau);
#pragma unroll
      for (int e = 0; e < 8; ++e) {
        if (sc[e] <= thr) {
          int kg = keybase + mw * 32 + (e >> 2) * 16 + hi * 4 + (e & 3);
          unsigned long long v = ((unsigned long long)ford(sc[e]) << 32) | (unsigned)kg;
          if (v < hp[7]) {
#pragma unroll
            for (int j = 7; j >= 1; --j) {
              unsigned long long aa = hp[j - 1];
              unsigned long long mx = aa > v ? aa : v;
              hp[j] = (v < hp[j]) ? mx : hp[j];
            }
            hp[0] = hp[0] < v ? hp[0] : v;
            t8 = ford_inv((unsigned)(hp[7] >> 32));
            thr = fminf(t8, tau);
          }
        }
      }
    };
    if (mb0 <= fminf(t8f0, tau0)) slow(sc0, h0, t8f0, tau0);
    if (mb1 <= fminf(t8f1, tau1)) slow(sc1, h1, t8f1, tau1);

    smin0 = fminf(smin0, mb0);
    smin1 = fminf(smin1, mb1);

    // ---- publish tau components (max over hi of stream mins, per mw)
    float m40 = smin0, m41 = smin1;
    m40 = fmaxf(m40, __shfl_xor(m40, 16, 64));
    m40 = fmaxf(m40, __shfl_xor(m40, 32, 64));
    m41 = fmaxf(m41, __shfl_xor(m41, 16, 64));
    m41 = fmaxf(m41, __shfl_xor(m41, 32, 64));
    if (hi == 0) {
      tauh[par][0][ws][mw][lo4] = m40;
      tauh[par][1][ws][mw][lo4] = m41;
    }

    kqc0 = kqn0; kqc1 = kqn1;

    asm volatile("s_waitcnt lgkmcnt(0)" ::: "memory"); // tile reads + tau retired
    __builtin_amdgcn_s_barrier();                      // safe to overwrite buf^1
  }

  const int stream = mw * 4 + hi;
  size_t co0 = (((size_t)xrow0 * NSPLIT + split) * NSTREAM + stream) * 8;
  size_t co1 = (((size_t)xrow1 * NSPLIT + split) * NSTREAM + stream) * 8;
#pragma unroll
  for (int j = 0; j < 8; ++j) { cand[co0 + j] = h0[j]; cand[co1 + j] = h1[j]; }
}

// ---------------------------------------------------------------------------
// knn_refine: per row (one wave): 512 candidates -> top-16 by packed score,
// recompute those 16 in fp64, true top-8 (idx tiebreak), average values.
// ---------------------------------------------------------------------------
__global__ void knn_refine(const float* __restrict__ x,
                           const float* __restrict__ keys,
                           const float* __restrict__ values,
                           const unsigned long long* __restrict__ cand,
                           float* __restrict__ out) {
  const int row = blockIdx.x;
  const int lane = threadIdx.x;

  unsigned long long c[8];
  const unsigned long long* cr = cand + (size_t)row * (NSPLIT * NSTREAM * 8);
#pragma unroll
  for (int i = 0; i < 8; ++i) c[i] = cr[lane * 8 + i];

  const int g = lane >> 2, sub = lane & 3;
  int idxg = 0;

#pragma unroll
  for (int r = 0; r < 16; ++r) {
    unsigned long long m = c[0];
#pragma unroll
    for (int i = 1; i < 8; ++i) m = c[i] < m ? c[i] : m;
#pragma unroll
    for (int off = 32; off; off >>= 1) {
      unsigned long long o = shfl_xor_u64(m, off);
      m = o < m ? o : m;
    }
    if (g == r) idxg = (int)(m & 0xFFFFFFFFu);
#pragma unroll
    for (int i = 0; i < 8; ++i)
      if (c[i] == m) c[i] = ~0ULL;
  }

  const float* xr = x + (size_t)row * DDIM;
  const float* kr = keys + (size_t)idxg * DDIM;
  double s = 0.0;
#pragma unroll
  for (int d = 0; d < 64; d += 4) {
    int dd = sub * 64 + d;
    float4 xa = *(const float4*)(xr + dd);
    float4 ka = *(const float4*)(kr + dd);
    double d0 = (double)xa.x - (double)ka.x;
    double d1 = (double)xa.y - (double)ka.y;
    double d2 = (double)xa.z - (double)ka.z;
    double d3 = (double)xa.w - (double)ka.w;
    s += d0 * d0 + d1 * d1 + d2 * d2 + d3 * d3;
  }
  s += shfl_xor_f64(s, 1);
  s += shfl_xor_f64(s, 2);

  double dv = (sub == 0) ? s : 1e300;
  int di = idxg;
  int chosen[8];
#pragma unroll
  for (int r = 0; r < 8; ++r) {
    double m = dv; int mi = di;
#pragma unroll
    for (int off = 32; off; off >>= 1) {
      double om = shfl_xor_f64(m, off);
      int omi = __shfl_xor(mi, off, 64);
      if (om < m || (om == m && omi < mi)) { m = om; mi = omi; }
    }
    chosen[r] = mi;
    if (sub == 0 && di == mi) dv = 1e300;
  }

  if (lane < NCH) {
    double a = 0.0;
#pragma unroll
    for (int r = 0; r < 8; ++r) a += (double)values[(size_t)chosen[r] * NCH + lane];
    out[row * NCH + lane] = (float)(a * 0.125);
  }
}

// ---------------------------------------------------------------------------
extern "C" void kernel_launch(void* const* d_in, const int* in_sizes, int n_in,
                              void* d_out, int out_size, void* d_ws, size_t ws_size,
                              hipStream_t stream) {
  (void)in_sizes; (void)n_in; (void)out_size; (void)ws_size;
  const float* x      = (const float*)d_in[0];
  const float* keys   = (const float*)d_in[1];
  const float* values = (const float*)d_in[2];
  float* out = (float*)d_out;

  char* ws = (char*)d_ws;
  unsigned char* kbf = (unsigned char*)ws;                            // 32 MB transposed bf16 keys
  float* ksq = (float*)(ws + (size_t)N_KEYS * 512);                   // 256 KB
  unsigned long long* cand =
      (unsigned long long*)(ws + (size_t)N_KEYS * 512 + (size_t)N_KEYS * 4); // 16 MB

  transpose_keys<<<N_KEYS / 128, 256, 0, stream>>>(keys, kbf, ksq);
  knn_main<<<(B_ROWS / ROWS_PER_BLK) * NSPLIT, 256, 0, stream>>>(
      x, kbf, ksq, cand);
  knn_refine<<<B_ROWS, 64, 0, stream>>>(x, keys, values, cand, out);
}

// Round 5
// 318.556 us; speedup vs baseline: 1.2533x; 1.2533x over previous
//
#include <hip/hip_runtime.h>
#include <stdint.h>
#include <float.h>

// x[4096,256] f32, keys[65536,256] f32, values[65536,10] f32, k=8 (hardcoded).
#define B_ROWS 4096
#define N_KEYS 65536
#define DDIM 256
#define NCH 10

#define NSPLIT 8
#define SPLIT_KEYS (N_KEYS / NSPLIT)       // 8192
#define ROWS_PER_BLK 64
#define CHUNK_KEYS 64
#define NCHUNK (SPLIT_KEYS / CHUNK_KEYS)   // 128

typedef float f32x4 __attribute__((ext_vector_type(4)));
typedef short bf16x8 __attribute__((ext_vector_type(8)));

static __device__ __forceinline__ unsigned short f2bf(float f) {
  unsigned u = __float_as_uint(f);
  return (unsigned short)((u + 0x7FFFu + ((u >> 16) & 1u)) >> 16);
}
static __device__ __forceinline__ unsigned ford(float f) {
  unsigned u = __float_as_uint(f);
  return u ^ ((unsigned)((int)u >> 31) | 0x80000000u);
}
static __device__ __forceinline__ unsigned long long shfl_xor_u64(unsigned long long v, int m) {
  unsigned lo = __shfl_xor((unsigned)v, m, 64);
  unsigned hi = __shfl_xor((unsigned)(v >> 32), m, 64);
  return ((unsigned long long)hi << 32) | lo;
}
static __device__ __forceinline__ double shfl_xor_f64(double v, int m) {
  return __longlong_as_double((long long)shfl_xor_u64((unsigned long long)__double_as_longlong(v), m));
}
static __device__ __forceinline__ void gl_lds16(const void* g, void* l) {
  __builtin_amdgcn_global_load_lds(
      (const __attribute__((address_space(1))) unsigned int*)g,
      (__attribute__((address_space(3))) unsigned int*)l, 16, 0, 0);
}

// ---------------------------------------------------------------------------
// transpose_keys: bf16-convert + transpose + fused ksq. Output layout:
// [chunk64][koct 0..31][key64 0..63][16B] (32KB records): knn_main staging is
// a LINEAR 32KB copy; A-frag ds_read_b128s are 256B-contiguous per 16-lane
// phase (conflict-free).
// ---------------------------------------------------------------------------
__global__ __launch_bounds__(256) void transpose_keys(const float* __restrict__ keys,
                                                      unsigned char* __restrict__ kbf,
                                                      float* __restrict__ ksq) {
  __shared__ __align__(16) unsigned char T[128 * 512];
  const int t = threadIdx.x;
  const int lane = t & 63;
  const float4* src = (const float4*)(keys + (size_t)blockIdx.x * 128 * DDIM);
#pragma unroll
  for (int j = 0; j < 32; ++j) {
    int g = j * 256 + t;
    float4 v = src[g];
    int key = g >> 6;
    int u = lane >> 1, sub = lane & 1;
    unsigned lo = ((unsigned)f2bf(v.y) << 16) | f2bf(v.x);
    unsigned hi2 = ((unsigned)f2bf(v.w) << 16) | f2bf(v.z);
    unsigned long long p = ((unsigned long long)hi2 << 32) | lo;
    *(unsigned long long*)&T[key * 512 + ((u ^ (key & 7)) << 4) + (sub << 3)] = p;
    float ss = v.x * v.x + v.y * v.y + v.z * v.z + v.w * v.w;
#pragma unroll
    for (int off = 32; off; off >>= 1) ss += __shfl_xor(ss, off, 64);
    if (lane == 0) ksq[blockIdx.x * 128 + key] = ss;
  }
  __syncthreads();
  uint4* dst = (uint4*)(kbf + (size_t)blockIdx.x * 65536);
#pragma unroll
  for (int j = 0; j < 16; ++j) {
    int ou = j * 256 + t;
    int c64 = ou >> 11, rem = ou & 2047;
    int koct = rem >> 6, key64 = rem & 63;
    int keyl = c64 * 64 + key64;
    dst[ou] = *(const uint4*)&T[keyl * 512 + ((koct ^ (keyl & 7)) << 4)];
  }
}

// ---------------------------------------------------------------------------
// knn_main: 512 thr = 8 waves = 4 key-quarters (mw, 16 keys) x 2 row-halves
// (ws, 32 rows). 64 rows x one split in 128 chunks of 64 keys. 2 blocks/CU,
// 4 waves/SIMD. Selection = FILTER + APPEND: any score <= tau_row (lagged
// max of the row's 8 paired-stream minima, a proven upper bound on the row's
// true 8th-best) is appended (19-bit quantized score | 13-bit idx, u32) to a
// per-(row,split) global pool via an LDS row counter. No per-thread heaps.
// Overflowing a pool (count > CAP) is flagged via the count and triggers an
// exact rescan in knn_refine, so correctness never depends on CAP.
// ---------------------------------------------------------------------------
__global__ __launch_bounds__(512, 4) void knn_main(
    const float* __restrict__ x,
    const unsigned char* __restrict__ kbf,
    const float* __restrict__ ksqg,
    unsigned int* __restrict__ pools,
    unsigned int* __restrict__ counts,
    int CAP) {
  __shared__ __align__(16) unsigned char tiles[2][32768]; // 64KB double buffer
  __shared__ float tauh[2][2][2][16][4]; // [par][set][ws][lo4][mw] = 2KB
  __shared__ unsigned int rowcnt[64];

  const int t = threadIdx.x;
  const int lane = t & 63;
  const int wv = t >> 6;          // 0..7
  const int mw = wv & 3;          // key quarter (16 keys)
  const int ws = wv >> 2;         // row half (32 rows)
  const int lo4 = lane & 15;
  const int hi = lane >> 4;

  const int split = blockIdx.x & (NSPLIT - 1);
  const int rb = (blockIdx.x >> 3) * ROWS_PER_BLK;
  const int sb = split * SPLIT_KEYS;

  const int xrow0 = rb + ws * 32 + lo4;
  const int xrow1 = xrow0 + 16;
  const int rl0 = ws * 32 + lo4, rl1 = rl0 + 16;

  bf16x8 xb0[8], xb1[8];
#pragma unroll
  for (int s = 0; s < 8; ++s) {
    const float* p0 = x + (size_t)xrow0 * DDIM + s * 32 + hi * 8;
    const float* p1 = x + (size_t)xrow1 * DDIM + s * 32 + hi * 8;
    float4 a = *(const float4*)p0, b = *(const float4*)(p0 + 4);
    float4 c = *(const float4*)p1, d = *(const float4*)(p1 + 4);
    union { unsigned short us[8]; bf16x8 v; } u0, u1;
    u0.us[0]=f2bf(a.x); u0.us[1]=f2bf(a.y); u0.us[2]=f2bf(a.z); u0.us[3]=f2bf(a.w);
    u0.us[4]=f2bf(b.x); u0.us[5]=f2bf(b.y); u0.us[6]=f2bf(b.z); u0.us[7]=f2bf(b.w);
    u1.us[0]=f2bf(c.x); u1.us[1]=f2bf(c.y); u1.us[2]=f2bf(c.z); u1.us[3]=f2bf(c.w);
    u1.us[4]=f2bf(d.x); u1.us[5]=f2bf(d.y); u1.us[6]=f2bf(d.z); u1.us[7]=f2bf(d.w);
    xb0[s] = u0.v; xb1[s] = u1.v;
  }

  float smin0 = FLT_MAX, smin1 = FLT_MAX;
  const unsigned char* srcbase = kbf + ((size_t)split * NCHUNK << 15);
  const size_t pb0 = ((size_t)xrow0 * NSPLIT + split) * (size_t)CAP;
  const size_t pb1 = ((size_t)xrow1 * NSPLIT + split) * (size_t)CAP;

  auto STAGE = [&](int c, int buf) { // linear 32KB, 4 x 16B per thread
    const unsigned char* src = srcbase + ((size_t)c << 15);
    unsigned char* wb = (unsigned char*)tiles[buf] + ((wv * 64) << 4);
#pragma unroll
    for (int i = 0; i < 4; ++i)
      gl_lds16(src + (((i * 512) + t) << 4), wb + ((i * 512) << 4));
  };

  f32x4 a0, a1;
  float sc0[4], sc1[4];

  auto COMPUTE = [&](int c) { // MFMA + scores for chunk c (tile must be ready)
    const unsigned char* tile = tiles[c & 1];
    a0 = 0.0f; a1 = 0.0f;
#pragma unroll
    for (int s = 0; s < 8; ++s) {
      const unsigned char* rp = tile + (s * 4 + hi) * 1024 + (mw * 16 + lo4) * 16;
      bf16x8 af = *(const bf16x8*)rp;
      a0 = __builtin_amdgcn_mfma_f32_16x16x32_bf16(af, xb0[s], a0, 0, 0, 0);
      a1 = __builtin_amdgcn_mfma_f32_16x16x32_bf16(af, xb1[s], a1, 0, 0, 0);
    }
    float4 kq = *(const float4*)(ksqg + sb + c * CHUNK_KEYS + mw * 16 + hi * 4);
#pragma unroll
    for (int i = 0; i < 4; ++i) {
      sc0[i] = fmaf(-2.0f, a0[i], ((const float*)&kq)[i]);
      sc1[i] = fmaf(-2.0f, a1[i], ((const float*)&kq)[i]);
    }
    float mb0 = fminf(fminf(sc0[0], sc0[1]), fminf(sc0[2], sc0[3]));
    float mb1 = fminf(fminf(sc1[0], sc1[1]), fminf(sc1[2], sc1[3]));
    smin0 = fminf(smin0, mb0);
    smin1 = fminf(smin1, mb1);
  };

  auto PUBLISH = [&](int par) {
    // pair streams across hi (xor16), then max over the wave's 2 pairs (xor32)
    float p0 = fminf(smin0, __shfl_xor(smin0, 16, 64));
    p0 = fmaxf(p0, __shfl_xor(p0, 32, 64));
    float p1 = fminf(smin1, __shfl_xor(smin1, 16, 64));
    p1 = fmaxf(p1, __shfl_xor(p1, 32, 64));
    if (hi == 0) {
      tauh[par][0][ws][lo4][mw] = p0;
      tauh[par][1][ws][lo4][mw] = p1;
    }
  };

  auto APPEND = [&](int c, int par) { // gate by lagged tau, append to pools
    float4 t0 = *(const float4*)&tauh[par][0][ws][lo4][0];
    float4 t1 = *(const float4*)&tauh[par][1][ws][lo4][0];
    float tau0 = fmaxf(fmaxf(t0.x, t0.y), fmaxf(t0.z, t0.w));
    float tau1 = fmaxf(fmaxf(t1.x, t1.y), fmaxf(t1.z, t1.w));
    int kloc = c * CHUNK_KEYS + mw * 16 + hi * 4; // idx within split
#pragma unroll
    for (int e = 0; e < 4; ++e) {
      if (sc0[e] <= tau0) {
        unsigned slot = atomicAdd(&rowcnt[rl0], 1u);
        if ((int)slot < CAP)
          pools[pb0 + slot] = (ford(sc0[e]) & 0xFFFFE000u) | (unsigned)(kloc + e);
      }
      if (sc1[e] <= tau1) {
        unsigned slot = atomicAdd(&rowcnt[rl1], 1u);
        if ((int)slot < CAP)
          pools[pb1 + slot] = (ford(sc1[e]) & 0xFFFFE000u) | (unsigned)(kloc + e);
      }
    }
  };

  // ---- prologue + peeled chunk 0 (self-tau: avoids the tau=inf flood)
  if (t < 64) rowcnt[t] = 0;
  STAGE(0, 0);
  __syncthreads();
  STAGE(1, 1);
  COMPUTE(0);
  PUBLISH(0);
  PUBLISH(1);
  __syncthreads();
  APPEND(0, 0);

#pragma unroll 1
  for (int c = 1; c < NCHUNK; ++c) {
    const int cn = (c + 1 < NCHUNK) ? c + 1 : c;
    STAGE(cn, (c + 1) & 1);
    COMPUTE(c);
    APPEND(c, (c - 1) & 1); // lagged tau (valid upper bound; parity race-free)
    PUBLISH(c & 1);
    __syncthreads();
  }

  __syncthreads();
  if (t < 64) counts[(size_t)(rb + t) * NSPLIT + split] = rowcnt[t];
}

// ---------------------------------------------------------------------------
// knn_refine: per row (1 wave): scan the row's 8 pools (or exact-rescan any
// overflowed split) into per-lane top-8 (u64 = qscore|fullidx), tournament
// top-24, fp64-exact recompute, true top-8 (idx tiebreak), average values.
// ---------------------------------------------------------------------------
__global__ __launch_bounds__(64) void knn_refine(
    const float* __restrict__ x,
    const float* __restrict__ keys,
    const float* __restrict__ ksq,
    const float* __restrict__ values,
    const unsigned int* __restrict__ pools,
    const unsigned int* __restrict__ counts,
    int CAP,
    float* __restrict__ out) {
  __shared__ float4 xl[64];
  const int row = blockIdx.x;
  const int lane = threadIdx.x;

  xl[lane] = ((const float4*)(x + (size_t)row * DDIM))[lane];
  __syncthreads();

  unsigned long long h[8];
#pragma unroll
  for (int i = 0; i < 8; ++i) h[i] = ~0ULL;

  auto insert = [&](unsigned long long v) {
    if (v < h[7]) {
#pragma unroll
      for (int j = 7; j >= 1; --j) {
        unsigned long long a = h[j - 1];
        unsigned long long mx = a > v ? a : v;
        h[j] = (v < h[j]) ? mx : h[j];
      }
      h[0] = h[0] < v ? h[0] : v;
    }
  };

  for (int s = 0; s < NSPLIT; ++s) {
    unsigned cnt = counts[(size_t)row * NSPLIT + s];
    if ((int)cnt <= CAP) {
      const unsigned int* pp = pools + ((size_t)row * NSPLIT + s) * (size_t)CAP;
      for (int i = lane; i < (int)cnt; i += 64) {
        unsigned p = pp[i];
        unsigned long long v = ((unsigned long long)p << 17)
                             | (unsigned)(s * SPLIT_KEYS + (p & 0x1FFFu));
        insert(v);
      }
    } else {
      // overflow fallback: exact fp32 rescan of this split (rare/never)
      for (int kk = lane; kk < SPLIT_KEYS; kk += 64) {
        int gk = s * SPLIT_KEYS + kk;
        const float4* kr = (const float4*)(keys + (size_t)gk * DDIM);
        float acc = 0.f;
#pragma unroll 8
        for (int d = 0; d < 64; ++d) {
          float4 kv = kr[d], xv = xl[d];
          acc = fmaf(kv.x, xv.x, acc); acc = fmaf(kv.y, xv.y, acc);
          acc = fmaf(kv.z, xv.z, acc); acc = fmaf(kv.w, xv.w, acc);
        }
        float sc = fmaf(-2.0f, acc, ksq[gk]);
        unsigned p = (ford(sc) & 0xFFFFE000u) | (unsigned)kk;
        insert(((unsigned long long)p << 17) | (unsigned)gk);
      }
    }
  }

  // ---- tournament: top-24 by quantized score (u64 unique: idx in low bits)
  int myidx = 0;
#pragma unroll 1
  for (int r = 0; r < 24; ++r) {
    unsigned long long m = h[0];
#pragma unroll
    for (int off = 32; off; off >>= 1) {
      unsigned long long o = shfl_xor_u64(m, off);
      m = o < m ? o : m;
    }
    if (lane == r) myidx = (int)(m & 0x1FFFFu);
    if (h[0] == m) {
#pragma unroll
      for (int i = 0; i < 7; ++i) h[i] = h[i + 1];
      h[7] = ~0ULL;
    }
  }

  // ---- exact fp64 distance for my candidate
  double dv = 1e300;
  if (lane < 24) {
    const float4* kr = (const float4*)(keys + (size_t)myidx * DDIM);
    double s = 0.0;
#pragma unroll 8
    for (int d = 0; d < 64; ++d) {
      float4 kv = kr[d], xv = xl[d];
      double d0 = (double)xv.x - (double)kv.x;
      double d1 = (double)xv.y - (double)kv.y;
      double d2 = (double)xv.z - (double)kv.z;
      double d3 = (double)xv.w - (double)kv.w;
      s += d0 * d0 + d1 * d1 + d2 * d2 + d3 * d3;
    }
    dv = s;
  }

  int di = myidx;
  int chosen[8];
#pragma unroll
  for (int r = 0; r < 8; ++r) {
    double m = dv; int mi = di;
#pragma unroll
    for (int off = 32; off; off >>= 1) {
      double om = shfl_xor_f64(m, off);
      int omi = __shfl_xor(mi, off, 64);
      if (om < m || (om == m && omi < mi)) { m = om; mi = omi; }
    }
    chosen[r] = mi;
    if (di == mi && dv < 1e300) dv = 1e300;
  }

  if (lane < NCH) {
    double a = 0.0;
#pragma unroll
    for (int r = 0; r < 8; ++r) a += (double)values[(size_t)chosen[r] * NCH + lane];
    out[row * NCH + lane] = (float)(a * 0.125);
  }
}

// ---------------------------------------------------------------------------
extern "C" void kernel_launch(void* const* d_in, const int* in_sizes, int n_in,
                              void* d_out, int out_size, void* d_ws, size_t ws_size,
                              hipStream_t stream) {
  (void)in_sizes; (void)n_in; (void)out_size;
  const float* x      = (const float*)d_in[0];
  const float* keys   = (const float*)d_in[1];
  const float* values = (const float*)d_in[2];
  float* out = (float*)d_out;

  char* ws = (char*)d_ws;
  unsigned char* kbf = (unsigned char*)ws;                 // 32 MB transposed bf16 keys
  float* ksq   = (float*)(ws + 33554432);                  // 256 KB
  unsigned int* counts = (unsigned int*)(ws + 33554432 + 262144); // 128 KB
  unsigned int* pools  = (unsigned int*)(ws + 33554432 + 262144 + 131072);

  size_t base = 33554432 + 262144 + 131072;
  size_t cap = (ws_size > base) ? (ws_size - base) / ((size_t)B_ROWS * NSPLIT * 4) : 32;
  if (cap < 32) cap = 32;
  if (cap > 2048) cap = 2048;
  int CAP = (int)cap;

  transpose_keys<<<N_KEYS / 128, 256, 0, stream>>>(keys, kbf, ksq);
  knn_main<<<(B_ROWS / ROWS_PER_BLK) * NSPLIT, 512, 0, stream>>>(
      x, kbf, ksq, pools, counts, CAP);
  knn_refine<<<B_ROWS, 64, 0, stream>>>(x, keys, ksq, values, pools, counts, CAP, out);
}